// Round 7
// baseline (141.621 us; speedup 1.0000x reference)
//
#include <hip/hip_runtime.h>
#include <hip/hip_bf16.h>
#include <limits.h>

typedef __attribute__((ext_vector_type(8))) short short8;
typedef __attribute__((ext_vector_type(4))) float f32x4;
typedef __attribute__((ext_vector_type(16))) float f32x16;

#define NN 8000
#define NCOL 4096      // 8*512 merged columns
#define KBINS 352      // NEST-1 == TOTAL_BINS
#define QPAD 640       // 583 padded
#define QH 320         // q rows per block (2 q-halves)
#define BN 128         // cols per block
#define KC 4           // k chunks (grid 32x2x4 = 256 blocks = 1/CU)
#define NTILE 64       // folded K padded: 64 tiles of 64 (n>=4000 zeroed, tile 63 all-zero)
#define KSTEP 16       // tiles per chunk: 64 = 4*16 exact
#define CUTQ 4
#define T_ 512
#define WFB 64         // packed band width for W_freq
#define WQB 20         // packed band width for W_quef

#define GLL16(g, l) __builtin_amdgcn_global_load_lds( \
    (const __attribute__((address_space(1))) unsigned int*)(g), \
    (__attribute__((address_space(3))) unsigned int*)(l), 16, 0, 0)

static __device__ __forceinline__ ushort bfc(float f){
  __hip_bfloat16 h = __float2bfloat16(f);
  return *reinterpret_cast<ushort*>(&h);
}
static __device__ __forceinline__ float b2f(ushort u){
  unsigned v = ((unsigned)u) << 16; float f; __builtin_memcpy(&f, &v, 4); return f;
}

// cosg[kt][q][slot-swizzled 64]: bf16(cos(2pi*((q*n)%8000)/8000)), 0 for pad rows q>=HQI.
// 8-bf16 slot s8 stored at s8 ^ (q&7)  -> conflict-free ds_read_b128 later.
__global__ void gen_cos_k(ushort* __restrict__ cosg, int HQI){
  int n = blockIdx.x*256 + threadIdx.x;   // n < 4096
  int q = blockIdx.y;
  float v = 0.f;
  if (q < HQI){
    int m = (q*n) % NN;                            // exact integer angle reduction
    v = cosf((float)m * 7.8539816339744831e-4f);   // 2*pi/8000
  }
  int kt = n >> 6, s8 = (n >> 3) & 7, e = n & 7;
  cosg[(size_t)kt*(QPAD*64) + (size_t)q*64 + (((s8 ^ (q & 7)) << 3) | e)] = bfc(v);
}

// symmetric fold of dx -> bf16, pre-swizzled & k-tiled for global_load_lds staging:
//   xf[0]=x[0]; xf[n]=x[n]+x[8000-n] (1<=n<4000); xf[4000]=x[4000]; xf[n>4000]=0
// layout: xf[kt][row][64] with 8-bf16 slot s8 stored at s8^(row&7).
__global__ __launch_bounds__(512) void fold_k(const float* __restrict__ dx,
                                              ushort* __restrict__ xf){
  int row = blockIdx.x;
  int tid = threadIdx.x;
  const float* rp = dx + (size_t)row*NN;
  int n0 = tid*8;                                  // 0..4088
  f32x4 p0 = *(const f32x4*)(rp + n0);
  f32x4 p1 = *(const f32x4*)(rp + n0 + 4);
  f32x4 ma = *(const f32x4*)(rp + 7996 - n0);
  f32x4 mb = *(const f32x4*)(rp + 7992 - n0);
  float ms = rp[n0 ? NN - n0 : 0];
  float pr[8] = {p0[0],p0[1],p0[2],p0[3],p1[0],p1[1],p1[2],p1[3]};
  float mi[8] = {n0 ? ms : 0.f, ma[3],ma[2],ma[1],ma[0],mb[3],mb[2],mb[1]};
  short8 o;
  #pragma unroll
  for (int e=0;e<8;e++){
    int n = n0 + e;
    float v = (n < 4000) ? pr[e] + mi[e] : ((n == 4000) ? pr[e] : 0.f);
    o[e] = (short)bfc(v);
  }
  int kt = n0 >> 6, s8 = (n0 >> 3) & 7;
  *(short8*)(&xf[((size_t)kt*NCOL + row)*64 + ((s8 ^ (row & 7)) << 3)]) = o;
}

// nonzero-support scan of a band matrix row -> [lo, hi); empty rows -> [0,0)
__global__ void bounds_k(const float* __restrict__ W, int width,
                         int* __restrict__ lo, int* __restrict__ hi){
  __shared__ int slo, shi;
  int r = blockIdx.x;
  if (threadIdx.x==0){ slo = INT_MAX; shi = -1; }
  __syncthreads();
  int mylo = INT_MAX, myhi = -1;
  for (int c = threadIdx.x; c < width; c += 256){
    if (W[(size_t)r*width + c] != 0.f){ if (c < mylo) mylo = c; if (c > myhi) myhi = c; }
  }
  atomicMin(&slo, mylo); atomicMax(&shi, myhi);
  __syncthreads();
  if (threadIdx.x==0){
    if (shi < 0){ lo[r] = 0; hi[r] = 0; }
    else        { lo[r] = slo; hi[r] = shi + 1; }
  }
}

// pack band matrix rows into fixed-width TRANSPOSED banded form: WT[j][r], j<bw
__global__ void pack_k(const float* __restrict__ W, const int* __restrict__ lo,
                       const int* __restrict__ hi, int width, int bw,
                       float* __restrict__ WT){
  int r = blockIdx.x;
  int l = lo[r], h = hi[r];
  for (int j = threadIdx.x; j < bw; j += 64){
    float v = 0.f;
    if (l + j < h) v = W[(size_t)r*width + l + j];
    WT[(size_t)j*KBINS + r] = v;
  }
}

// part[kc][col][q] (bf16) = sum_{k in chunk} xf[col][k]*cos[q][k]
// Block: 320q x 128col, BK=64, dbuf LDS 112KB (1 block/CU), 8 waves (2q x 4col),
// wave tile 160q x 32col as 5x1 mfma_32x32x16 tiles. Both operands staged via
// global_load_lds from pre-swizzled tables -> zero staging VALU in the K-loop.
__global__ __launch_bounds__(512, 2) void gemm_k(const ushort* __restrict__ xf,
                                                 const ushort* __restrict__ cosg,
                                                 ushort* __restrict__ part){
  __shared__ ushort As[2][QH*64];    // cos tiles, 40 KB each, slot-swizzled
  __shared__ ushort Bs[2][BN*64];    // folded dx tiles, 16 KB each, slot-swizzled
  int tid = threadIdx.x;
  int nb = blockIdx.x, qh = blockIdx.y, kc = blockIdx.z;
  int lane = tid & 63, widx = tid >> 6;
  int wm = widx & 1, wn = widx >> 1;          // wm: q-half(160), wn: col-quarter(32)
  int l31 = lane & 31, lh = lane >> 5;
  int kt0 = kc*KSTEP, ktE = kt0 + KSTEP;

  const ushort* ag0 = cosg + (size_t)qh*(QH*64) + tid*8;
  const ushort* bg0 = xf + (size_t)nb*(BN*64) + tid*8;

  #define STAGE(kt_, buf_) { \
    const ushort* ag_ = ag0 + (size_t)(kt_)*(QPAD*64); \
    _Pragma("unroll") \
    for (int i_=0;i_<5;i_++) GLL16(ag_ + i_*4096, &As[buf_][tid*8 + i_*4096]); \
    const ushort* bg_ = bg0 + (size_t)(kt_)*(NCOL*64); \
    GLL16(bg_,        &Bs[buf_][tid*8]); \
    GLL16(bg_ + 4096, &Bs[buf_][tid*8 + 4096]); }

  f32x16 acc[5];
  #pragma unroll
  for (int a=0;a<5;a++) acc[a] = (f32x16)0.f;

  STAGE(kt0, 0);
  __syncthreads();

  int cur = 0;
  for (int kt = kt0; kt < ktE; ++kt){
    if (kt + 1 < ktE) STAGE(kt+1, cur^1);    // issue next-tile loads BEFORE compute
    const ushort* Ac = &As[cur][0];
    const ushort* Bc = &Bs[cur][0];
    #pragma unroll
    for (int p=0;p<4;p++){                   // 4 k=16 passes within BK=64
      int brow = wn*32 + l31;
      short8 dfr = *(const short8*)(Bc + brow*64 + ((((p<<1)|lh) ^ (brow & 7)) << 3));
      short8 cfr[5];
      #pragma unroll
      for (int a=0;a<5;a++){
        int arow = wm*160 + a*32 + l31;
        cfr[a] = *(const short8*)(Ac + arow*64 + ((((p<<1)|lh) ^ (arow & 7)) << 3));
      }
      __builtin_amdgcn_s_setprio(1);
      #pragma unroll
      for (int a=0;a<5;a++)
        acc[a] = __builtin_amdgcn_mfma_f32_32x32x16_bf16(dfr, cfr[a], acc[a], 0,0,0);
      __builtin_amdgcn_s_setprio(0);
    }
    __syncthreads();                         // drains GLL vmcnt; next tile visible
    cur ^= 1;
  }

  // D layout (32x32): n(q) = lane&31, m(col) = (r&3) + 8*(r>>2) + 4*(lane>>5)
  ushort* pb = part + (size_t)kc*NCOL*QPAD;
  #pragma unroll
  for (int a=0;a<5;a++){
    int q = qh*QH + wm*160 + a*32 + l31;
    int colb = nb*BN + wn*32 + 4*lh;
    #pragma unroll
    for (int r=0;r<16;r++){
      int col = colb + (r&3) + 8*(r>>2);
      pb[(size_t)col*QPAD + q] = bfc(acc[a][r]);
    }
  }
}

// per (b,t) column: partial-sum + nonlinear -> fixed-width banded matvecs -> harmonic gather
__global__ __launch_bounds__(384) void fuse_k(const float* __restrict__ dx,
        const ushort* __restrict__ part,
        const float* __restrict__ WfT, const float* __restrict__ WqT,
        const int* __restrict__ fLo, const int* __restrict__ qLo,
        float* __restrict__ out, int HFI, int HQI){
  __shared__ float xr[2368];
  __shared__ float yq[QPAD];
  __shared__ float tl0[KBINS];
  __shared__ float tlq[KBINS];
  int col = blockIdx.x;
  int b = col >> 9, t = col & 511;
  int tid = threadIdx.x;
  const float invs = 0.011180339887498949f;   // 1/sqrt(8000)

  for (int f = tid; f < 2368; f += 384) xr[f] = (f < HFI) ? dx[(size_t)col*NN + f] : 0.f;
  const ushort* pc = part + (size_t)col*QPAD;
  for (int q = tid; q < QPAD; q += 384){
    float y = 0.f;
    if (q < HQI){
      float s = 0.f;
      #pragma unroll
      for (int kc=0; kc<KC; kc++) s += b2f(pc[(size_t)kc*NCOL*QPAD + q]);
      s *= invs;
      if (q >= CUTQ && s > 0.f) y = powf(s, 0.6f);
    }
    yq[q] = y;
  }
  __syncthreads();

  if (tid < KBINS){
    int k = tid;
    int lo = fLo[k];
    float aF = 0.f;
    #pragma unroll
    for (int j=0;j<WFB;j++) aF += WfT[j*KBINS + k] * xr[lo + j];
    int ql = qLo[k];
    float aQ = 0.f;
    #pragma unroll
    for (int j=0;j<WQB;j++) aQ += WqT[j*KBINS + k] * yq[ql + j];
    tl0[k] = aF; tlq[k] = aQ;
  }
  __syncthreads();

  const int hids[6] = {0,48,76,96,111,124};   // argmin|CF - (k+1)*27.5|
  for (int u = tid; u < 12*KBINS; u += 384){
    int j = u / KBINS;
    int k = u - j*KBINS;
    int h = hids[(j < 6) ? j : j - 6];
    float v;
    if (j < 6) v = (k + h < KBINS) ? tl0[k + h] : 0.f;   // har_s: shift left, pad end
    else       v = (k >= h)        ? tlq[k - h] : 0.f;   // har_c: shift right, pad front
    out[(((size_t)b*12 + j)*T_ + t)*KBINS + k] = v;
  }
}

extern "C" void kernel_launch(void* const* d_in, const int* in_sizes, int n_in,
                              void* d_out, int out_size, void* d_ws, size_t ws_size,
                              hipStream_t stream){
  const float* dx = (const float*)d_in[0];
  const float* Wf = (const float*)d_in[1];
  const float* Wq = (const float*)d_in[2];
  int HFI = in_sizes[1] / KBINS;   // runtime-derived (banker's-rounding safe)
  int HQI = in_sizes[2] / KBINS;
  float* out = (float*)d_out;
  char* ws = (char*)d_ws;

  ushort* cosg = (ushort*)ws;
  size_t off = (size_t)NTILE*QPAD*64*2;                        // 5.24 MB
  ushort* xf = (ushort*)(ws + off); off += (size_t)NTILE*NCOL*64*2;   // 33.55 MB
  ushort* part = (ushort*)(ws + off); off += (size_t)KC*NCOL*QPAD*2;  // 20.97 MB
  int* fLo = (int*)(ws+off); off += KBINS*4;
  int* fHi = (int*)(ws+off); off += KBINS*4;
  int* qLo = (int*)(ws+off); off += KBINS*4;
  int* qHi = (int*)(ws+off); off += KBINS*4;
  float* WfT = (float*)(ws+off); off += (size_t)WFB*KBINS*4;   // 90 KB
  float* WqT = (float*)(ws+off); off += (size_t)WQB*KBINS*4;   // 28 KB
  (void)n_in; (void)out_size; (void)ws_size;

  gen_cos_k<<<dim3(16, QPAD), 256, 0, stream>>>(cosg, HQI);     // n < 4096
  fold_k<<<NCOL, 512, 0, stream>>>(dx, xf);
  bounds_k<<<KBINS, 256, 0, stream>>>(Wf, HFI, fLo, fHi);
  bounds_k<<<KBINS, 256, 0, stream>>>(Wq, HQI, qLo, qHi);
  pack_k<<<KBINS, 64, 0, stream>>>(Wf, fLo, fHi, HFI, WFB, WfT);
  pack_k<<<KBINS, 64, 0, stream>>>(Wq, qLo, qHi, HQI, WQB, WqT);
  gemm_k<<<dim3(NCOL/BN, QPAD/QH, KC), 512, 0, stream>>>(xf, cosg, part);
  fuse_k<<<NCOL, 384, 0, stream>>>(dx, part, WfT, WqT, fLo, qLo, out, HFI, HQI);
}

// Round 8
// 138.228 us; speedup vs baseline: 1.0246x; 1.0246x over previous
//
#include <hip/hip_runtime.h>
#include <hip/hip_bf16.h>
#include <limits.h>

typedef __attribute__((ext_vector_type(8))) short short8;
typedef __attribute__((ext_vector_type(4))) float f32x4;
typedef __attribute__((ext_vector_type(16))) float f32x16;

#define NN 8000
#define NCOL 4096      // 8*512 merged columns
#define KBINS 352      // NEST-1 == TOTAL_BINS
#define QPAD 640       // 583 padded
#define QH 160         // q rows per block (4 q-blocks)
#define BN 128         // cols per block
#define KC 4           // k chunks (grid 32x4x4 = 512 blocks = 2/CU)
#define NTILE 64       // folded K padded: 64 tiles of 64 (n>4000 zeroed)
#define KSTEP 16       // tiles per chunk: 64 = 4*16 exact
#define CUTQ 4
#define T_ 512
#define WFB 64         // packed band width for W_freq
#define WQB 20         // packed band width for W_quef

#define GLL16(g, l) __builtin_amdgcn_global_load_lds( \
    (const __attribute__((address_space(1))) unsigned int*)(g), \
    (__attribute__((address_space(3))) unsigned int*)(l), 16, 0, 0)

static __device__ __forceinline__ ushort bfc(float f){
  __hip_bfloat16 h = __float2bfloat16(f);
  return *reinterpret_cast<ushort*>(&h);
}
static __device__ __forceinline__ float b2f(ushort u){
  unsigned v = ((unsigned)u) << 16; float f; __builtin_memcpy(&f, &v, 4); return f;
}

// cosg[kt][q][slot-swizzled 64]: bf16(cos(2pi*((q*n)%8000)/8000)), 0 for pad rows q>=HQI.
// 8-bf16 slot s8 stored at s8 ^ (q&7)  -> matches gemm's ds_read slot swizzle.
__global__ void gen_cos_k(ushort* __restrict__ cosg, int HQI){
  int n = blockIdx.x*256 + threadIdx.x;   // n < 4096
  int q = blockIdx.y;
  float v = 0.f;
  if (q < HQI){
    int m = (q*n) % NN;                            // exact integer angle reduction
    v = cosf((float)m * 7.8539816339744831e-4f);   // 2*pi/8000
  }
  int kt = n >> 6, s8 = (n >> 3) & 7, e = n & 7;
  cosg[(size_t)kt*(QPAD*64) + (size_t)q*64 + (((s8 ^ (q & 7)) << 3) | e)] = bfc(v);
}

// symmetric fold of dx -> bf16, pre-swizzled & k-tiled for global_load_lds staging:
//   xf[0]=x[0]; xf[n]=x[n]+x[8000-n] (1<=n<4000); xf[4000]=x[4000]; xf[n>4000]=0
// Mirror half staged in pad-indexed LDS so ALL global reads are coalesced forward.
#define PADI(j) ((j) + ((j) >> 5))
__global__ __launch_bounds__(512) void fold_k(const float* __restrict__ dx,
                                              ushort* __restrict__ xf){
  __shared__ float sbuf[4232];                     // PADI(4103)=4231
  int row = blockIdx.x;
  int t = threadIdx.x;
  const float* rp = dx + (size_t)row*NN;

  // stage sbuf[j] = x[3896+j], j in [0,4104)  (coalesced forward loads)
  {
    int j0 = t*8;                                  // 0..4088
    f32x4 v0 = *(const f32x4*)(rp + 3896 + j0);
    f32x4 v1 = *(const f32x4*)(rp + 3896 + j0 + 4);
    #pragma unroll
    for (int e=0;e<4;e++) sbuf[PADI(j0+e)] = v0[e];
    #pragma unroll
    for (int e=0;e<4;e++) sbuf[PADI(j0+4+e)] = v1[e];
    if (t == 0){
      #pragma unroll
      for (int e=0;e<8;e++) sbuf[PADI(4096+e)] = rp[7992+e];
    }
  }
  __syncthreads();

  int n0 = t*8;                                    // 0..4088
  f32x4 p0 = *(const f32x4*)(rp + n0);
  f32x4 p1 = *(const f32x4*)(rp + n0 + 4);
  float pr[8] = {p0[0],p0[1],p0[2],p0[3],p1[0],p1[1],p1[2],p1[3]};
  short8 o;
  #pragma unroll
  for (int e=0;e<8;e++){
    int n = n0 + e;
    float v;
    if (n == 0)          v = pr[0];
    else if (n < 4000)   v = pr[e] + sbuf[PADI(4104 - n)];   // x[8000-n]
    else if (n == 4000)  v = pr[e];
    else                 v = 0.f;
    o[e] = (short)bfc(v);
  }
  int kt = n0 >> 6, s8 = (n0 >> 3) & 7;
  *(short8*)(&xf[((size_t)kt*NCOL + row)*64 + ((s8 ^ (row & 7)) << 3)]) = o;
}

// nonzero-support scan of a band matrix row -> [lo, hi); empty rows -> [0,0)
__global__ void bounds_k(const float* __restrict__ W, int width,
                         int* __restrict__ lo, int* __restrict__ hi){
  __shared__ int slo, shi;
  int r = blockIdx.x;
  if (threadIdx.x==0){ slo = INT_MAX; shi = -1; }
  __syncthreads();
  int mylo = INT_MAX, myhi = -1;
  for (int c = threadIdx.x; c < width; c += 256){
    if (W[(size_t)r*width + c] != 0.f){ if (c < mylo) mylo = c; if (c > myhi) myhi = c; }
  }
  atomicMin(&slo, mylo); atomicMax(&shi, myhi);
  __syncthreads();
  if (threadIdx.x==0){
    if (shi < 0){ lo[r] = 0; hi[r] = 0; }
    else        { lo[r] = slo; hi[r] = shi + 1; }
  }
}

// pack band matrix rows into fixed-width TRANSPOSED banded form: WT[j][r], j<bw
__global__ void pack_k(const float* __restrict__ W, const int* __restrict__ lo,
                       const int* __restrict__ hi, int width, int bw,
                       float* __restrict__ WT){
  int r = blockIdx.x;
  int l = lo[r], h = hi[r];
  for (int j = threadIdx.x; j < bw; j += 64){
    float v = 0.f;
    if (l + j < h) v = W[(size_t)r*width + l + j];
    WT[(size_t)j*KBINS + r] = v;
  }
}

// part[kc][col][q] (bf16) = sum_{k in chunk} xf[col][k]*cos[q][k]
// Block: 160q x 128col, BK=64, dbuf LDS 72KB -> 2 blocks/CU (drain overlap across
// blocks). 4 waves, wave tile 160q x 32col as 5 mfma_32x32x16 tiles. Pure-GLL
// staging from pre-swizzled tables: zero staging VALU in the K-loop.
__global__ __launch_bounds__(256, 2) void gemm_k(const ushort* __restrict__ xf,
                                                 const ushort* __restrict__ cosg,
                                                 ushort* __restrict__ part){
  __shared__ ushort As[2][QH*64];    // cos tiles, 20 KB each, slot-swizzled
  __shared__ ushort Bs[2][BN*64];    // folded dx tiles, 16 KB each, slot-swizzled
  int tid = threadIdx.x;
  int nb = blockIdx.x, qh = blockIdx.y, kc = blockIdx.z;
  int lane = tid & 63, wn = tid >> 6;         // wave covers cols [wn*32, wn*32+32)
  int l31 = lane & 31, lh = lane >> 5;
  int kt0 = kc*KSTEP, ktE = kt0 + KSTEP;

  const ushort* ag0 = cosg + (size_t)qh*(QH*64) + tid*8;
  const ushort* bg0 = xf + (size_t)nb*(BN*64) + tid*8;

  #define STAGE(kt_, buf_) { \
    const ushort* ag_ = ag0 + (size_t)(kt_)*(QPAD*64); \
    _Pragma("unroll") \
    for (int i_=0;i_<5;i_++) GLL16(ag_ + i_*2048, &As[buf_][tid*8 + i_*2048]); \
    const ushort* bg_ = bg0 + (size_t)(kt_)*(NCOL*64); \
    _Pragma("unroll") \
    for (int i_=0;i_<4;i_++) GLL16(bg_ + i_*2048, &Bs[buf_][tid*8 + i_*2048]); }

  f32x16 acc[5];
  #pragma unroll
  for (int a=0;a<5;a++) acc[a] = (f32x16)0.f;

  STAGE(kt0, 0);
  __syncthreads();

  int cur = 0;
  for (int kt = kt0; kt < ktE; ++kt){
    if (kt + 1 < ktE) STAGE(kt+1, cur^1);    // issue next-tile loads BEFORE compute
    const ushort* Ac = &As[cur][0];
    const ushort* Bc = &Bs[cur][0];
    #pragma unroll
    for (int p=0;p<4;p++){                   // 4 k=16 passes within BK=64
      int brow = wn*32 + l31;
      short8 dfr = *(const short8*)(Bc + brow*64 + ((((p<<1)|lh) ^ (brow & 7)) << 3));
      short8 cfr[5];
      #pragma unroll
      for (int a=0;a<5;a++){
        int arow = a*32 + l31;
        cfr[a] = *(const short8*)(Ac + arow*64 + ((((p<<1)|lh) ^ (arow & 7)) << 3));
      }
      __builtin_amdgcn_s_setprio(1);
      #pragma unroll
      for (int a=0;a<5;a++)
        acc[a] = __builtin_amdgcn_mfma_f32_32x32x16_bf16(dfr, cfr[a], acc[a], 0,0,0);
      __builtin_amdgcn_s_setprio(0);
    }
    __syncthreads();                         // drains GLL vmcnt; next tile visible
    cur ^= 1;
  }

  // D layout (32x32): n(q) = lane&31, m(col) = (r&3) + 8*(r>>2) + 4*(lane>>5)
  ushort* pb = part + (size_t)kc*NCOL*QPAD;
  #pragma unroll
  for (int a=0;a<5;a++){
    int q = qh*QH + a*32 + l31;
    int colb = nb*BN + wn*32 + 4*lh;
    #pragma unroll
    for (int r=0;r<16;r++){
      int col = colb + (r&3) + 8*(r>>2);
      pb[(size_t)col*QPAD + q] = bfc(acc[a][r]);
    }
  }
}

// per (b,t) column: partial-sum + nonlinear -> fixed-width banded matvecs -> harmonic gather
__global__ __launch_bounds__(384) void fuse_k(const float* __restrict__ dx,
        const ushort* __restrict__ part,
        const float* __restrict__ WfT, const float* __restrict__ WqT,
        const int* __restrict__ fLo, const int* __restrict__ qLo,
        float* __restrict__ out, int HFI, int HQI){
  __shared__ float xr[2368];
  __shared__ float yq[QPAD];
  __shared__ float tl0[KBINS];
  __shared__ float tlq[KBINS];
  int col = blockIdx.x;
  int b = col >> 9, t = col & 511;
  int tid = threadIdx.x;
  const float invs = 0.011180339887498949f;   // 1/sqrt(8000)

  for (int f = tid; f < 2368; f += 384) xr[f] = (f < HFI) ? dx[(size_t)col*NN + f] : 0.f;
  const ushort* pc = part + (size_t)col*QPAD;
  for (int q = tid; q < QPAD; q += 384){
    float y = 0.f;
    if (q < HQI){
      float s = 0.f;
      #pragma unroll
      for (int kc=0; kc<KC; kc++) s += b2f(pc[(size_t)kc*NCOL*QPAD + q]);
      s *= invs;
      if (q >= CUTQ && s > 0.f) y = powf(s, 0.6f);
    }
    yq[q] = y;
  }
  __syncthreads();

  if (tid < KBINS){
    int k = tid;
    int lo = fLo[k];
    float aF = 0.f;
    #pragma unroll
    for (int j=0;j<WFB;j++) aF += WfT[j*KBINS + k] * xr[lo + j];
    int ql = qLo[k];
    float aQ = 0.f;
    #pragma unroll
    for (int j=0;j<WQB;j++) aQ += WqT[j*KBINS + k] * yq[ql + j];
    tl0[k] = aF; tlq[k] = aQ;
  }
  __syncthreads();

  const int hids[6] = {0,48,76,96,111,124};   // argmin|CF - (k+1)*27.5|
  for (int u = tid; u < 12*KBINS; u += 384){
    int j = u / KBINS;
    int k = u - j*KBINS;
    int h = hids[(j < 6) ? j : j - 6];
    float v;
    if (j < 6) v = (k + h < KBINS) ? tl0[k + h] : 0.f;   // har_s: shift left, pad end
    else       v = (k >= h)        ? tlq[k - h] : 0.f;   // har_c: shift right, pad front
    out[(((size_t)b*12 + j)*T_ + t)*KBINS + k] = v;
  }
}

extern "C" void kernel_launch(void* const* d_in, const int* in_sizes, int n_in,
                              void* d_out, int out_size, void* d_ws, size_t ws_size,
                              hipStream_t stream){
  const float* dx = (const float*)d_in[0];
  const float* Wf = (const float*)d_in[1];
  const float* Wq = (const float*)d_in[2];
  int HFI = in_sizes[1] / KBINS;   // runtime-derived (banker's-rounding safe)
  int HQI = in_sizes[2] / KBINS;
  float* out = (float*)d_out;
  char* ws = (char*)d_ws;

  ushort* cosg = (ushort*)ws;
  size_t off = (size_t)NTILE*QPAD*64*2;                        // 5.24 MB
  ushort* xf = (ushort*)(ws + off); off += (size_t)NTILE*NCOL*64*2;   // 33.55 MB
  ushort* part = (ushort*)(ws + off); off += (size_t)KC*NCOL*QPAD*2;  // 20.97 MB
  int* fLo = (int*)(ws+off); off += KBINS*4;
  int* fHi = (int*)(ws+off); off += KBINS*4;
  int* qLo = (int*)(ws+off); off += KBINS*4;
  int* qHi = (int*)(ws+off); off += KBINS*4;
  float* WfT = (float*)(ws+off); off += (size_t)WFB*KBINS*4;   // 90 KB
  float* WqT = (float*)(ws+off); off += (size_t)WQB*KBINS*4;   // 28 KB
  (void)n_in; (void)out_size; (void)ws_size;

  gen_cos_k<<<dim3(16, QPAD), 256, 0, stream>>>(cosg, HQI);     // n < 4096
  fold_k<<<NCOL, 512, 0, stream>>>(dx, xf);
  bounds_k<<<KBINS, 256, 0, stream>>>(Wf, HFI, fLo, fHi);
  bounds_k<<<KBINS, 256, 0, stream>>>(Wq, HQI, qLo, qHi);
  pack_k<<<KBINS, 64, 0, stream>>>(Wf, fLo, fHi, HFI, WFB, WfT);
  pack_k<<<KBINS, 64, 0, stream>>>(Wq, qLo, qHi, HQI, WQB, WqT);
  gemm_k<<<dim3(NCOL/BN, QPAD/QH, KC), 256, 0, stream>>>(xf, cosg, part);
  fuse_k<<<NCOL, 384, 0, stream>>>(dx, part, WfT, WqT, fLo, qLo, out, HFI, HQI);
}

// Round 9
// 129.412 us; speedup vs baseline: 1.0943x; 1.0681x over previous
//
#include <hip/hip_runtime.h>
#include <hip/hip_bf16.h>
#include <limits.h>

typedef __attribute__((ext_vector_type(8))) short short8;
typedef __attribute__((ext_vector_type(4))) float f32x4;
typedef __attribute__((ext_vector_type(16))) float f32x16;

#define NN 8000
#define NCOL 4096      // 8*512 merged columns
#define KBINS 352      // NEST-1 == TOTAL_BINS
#define QPAD 640       // 583 padded
#define QH 160         // q rows per block (4 q-blocks)
#define BN 128         // cols per block
#define KC 4           // k chunks (grid 32x4x4 = 512 blocks = 2/CU)
#define NTILE 64       // folded K padded: 64 tiles of 64 (n>4000 zeroed)
#define KSTEP 16       // tiles per chunk: 64 = 4*16 exact
#define CUTQ 4
#define T_ 512
#define WFB 64         // packed band width for W_freq
#define WQB 20         // packed band width for W_quef

#define GLL16(g, l) __builtin_amdgcn_global_load_lds( \
    (const __attribute__((address_space(1))) unsigned int*)(g), \
    (__attribute__((address_space(3))) unsigned int*)(l), 16, 0, 0)

static __device__ __forceinline__ ushort bfc(float f){
  __hip_bfloat16 h = __float2bfloat16(f);
  return *reinterpret_cast<ushort*>(&h);
}
static __device__ __forceinline__ float b2f(ushort u){
  unsigned v = ((unsigned)u) << 16; float f; __builtin_memcpy(&f, &v, 4); return f;
}

// cosg[kt][q][slot-swizzled 64]: bf16(cos(2pi*((q*n)%8000)/8000)), 0 for pad rows q>=HQI.
__global__ void gen_cos_k(ushort* __restrict__ cosg, int HQI){
  int n = blockIdx.x*256 + threadIdx.x;   // n < 4096
  int q = blockIdx.y;
  float v = 0.f;
  if (q < HQI){
    int m = (q*n) % NN;                            // exact integer angle reduction
    v = cosf((float)m * 7.8539816339744831e-4f);   // 2*pi/8000
  }
  int kt = n >> 6, s8 = (n >> 3) & 7, e = n & 7;
  cosg[(size_t)kt*(QPAD*64) + (size_t)q*64 + (((s8 ^ (q & 7)) << 3) | e)] = bfc(v);
}

// symmetric fold of dx -> bf16, pre-swizzled & k-tiled for global_load_lds staging:
//   xf[0]=x[0]; xf[n]=x[n]+x[8000-n] (1<=n<4000); xf[4000]=x[4000]; xf[n>4000]=0
#define PADI(j) ((j) + ((j) >> 5))
__global__ __launch_bounds__(512) void fold_k(const float* __restrict__ dx,
                                              ushort* __restrict__ xf){
  __shared__ float sbuf[4232];                     // PADI(4103)=4231
  int row = blockIdx.x;
  int t = threadIdx.x;
  const float* rp = dx + (size_t)row*NN;
  {
    int j0 = t*8;
    f32x4 v0 = *(const f32x4*)(rp + 3896 + j0);
    f32x4 v1 = *(const f32x4*)(rp + 3896 + j0 + 4);
    #pragma unroll
    for (int e=0;e<4;e++) sbuf[PADI(j0+e)] = v0[e];
    #pragma unroll
    for (int e=0;e<4;e++) sbuf[PADI(j0+4+e)] = v1[e];
    if (t == 0){
      #pragma unroll
      for (int e=0;e<8;e++) sbuf[PADI(4096+e)] = rp[7992+e];
    }
  }
  __syncthreads();

  int n0 = t*8;
  f32x4 p0 = *(const f32x4*)(rp + n0);
  f32x4 p1 = *(const f32x4*)(rp + n0 + 4);
  float pr[8] = {p0[0],p0[1],p0[2],p0[3],p1[0],p1[1],p1[2],p1[3]};
  short8 o;
  #pragma unroll
  for (int e=0;e<8;e++){
    int n = n0 + e;
    float v;
    if (n == 0)          v = pr[0];
    else if (n < 4000)   v = pr[e] + sbuf[PADI(4104 - n)];   // x[8000-n]
    else if (n == 4000)  v = pr[e];
    else                 v = 0.f;
    o[e] = (short)bfc(v);
  }
  int kt = n0 >> 6, s8 = (n0 >> 3) & 7;
  *(short8*)(&xf[((size_t)kt*NCOL + row)*64 + ((s8 ^ (row & 7)) << 3)]) = o;
}

// bounds-scan + fixed-width transposed band-pack, both W matrices in one launch.
__global__ void bp_k(const float* __restrict__ Wf, const float* __restrict__ Wq,
                     int HFI, int HQI, int* __restrict__ fLo, int* __restrict__ qLo,
                     float* __restrict__ WfT, float* __restrict__ WqT){
  __shared__ int slo, shi;
  int r = blockIdx.x;
  bool isF = (blockIdx.y == 0);
  const float* W = isF ? Wf : Wq;
  int width = isF ? HFI : HQI;
  int bw    = isF ? WFB : WQB;
  float* WT = isF ? WfT : WqT;
  int* Lo   = isF ? fLo : qLo;
  if (threadIdx.x==0){ slo = INT_MAX; shi = -1; }
  __syncthreads();
  int mylo = INT_MAX, myhi = -1;
  for (int c = threadIdx.x; c < width; c += 256){
    if (W[(size_t)r*width + c] != 0.f){ if (c < mylo) mylo = c; if (c > myhi) myhi = c; }
  }
  atomicMin(&slo, mylo); atomicMax(&shi, myhi);
  __syncthreads();
  int l = (shi < 0) ? 0 : slo, h = (shi < 0) ? 0 : shi + 1;
  if (threadIdx.x==0) Lo[r] = l;
  for (int j = threadIdx.x; j < bw; j += 256){
    float v = 0.f;
    if (l + j < h) v = W[(size_t)r*width + l + j];
    WT[(size_t)j*KBINS + r] = v;
  }
}

// part[kc][col][q] (bf16) = sum_{k in chunk} xf[col][k]*cos[q][k]
// Block: 160q x 128col, BK=64, dbuf LDS 72KB (2 blocks/CU), 4 waves, wave tile
// 160q x 32col as 5 mfma_32x32x16. Pure-GLL staging; counted-vmcnt pipeline:
// next tile's 9 loads stay in flight across the barrier (never drain to 0).
__global__ __launch_bounds__(256, 2) void gemm_k(const ushort* __restrict__ xf,
                                                 const ushort* __restrict__ cosg,
                                                 ushort* __restrict__ part){
  __shared__ ushort As[2][QH*64];    // cos tiles, 20 KB each, slot-swizzled
  __shared__ ushort Bs[2][BN*64];    // folded dx tiles, 16 KB each, slot-swizzled
  int tid = threadIdx.x;
  int nb = blockIdx.x, qh = blockIdx.y, kc = blockIdx.z;
  int lane = tid & 63, wn = tid >> 6;
  int l31 = lane & 31, lh = lane >> 5;
  int kt0 = kc*KSTEP, ktE = kt0 + KSTEP;

  const ushort* ag0 = cosg + (size_t)qh*(QH*64) + tid*8;
  const ushort* bg0 = xf + (size_t)nb*(BN*64) + tid*8;

  #define STAGE(kt_, buf_) { \
    const ushort* ag_ = ag0 + (size_t)(kt_)*(QPAD*64); \
    _Pragma("unroll") \
    for (int i_=0;i_<5;i_++) GLL16(ag_ + i_*2048, &As[buf_][tid*8 + i_*2048]); \
    const ushort* bg_ = bg0 + (size_t)(kt_)*(NCOL*64); \
    _Pragma("unroll") \
    for (int i_=0;i_<4;i_++) GLL16(bg_ + i_*2048, &Bs[buf_][tid*8 + i_*2048]); }

  f32x16 acc[5];
  #pragma unroll
  for (int a=0;a<5;a++) acc[a] = (f32x16)0.f;

  STAGE(kt0, 0);                             // 9 loads in flight

  int cur = 0;
  for (int kt = kt0; kt < ktE; ++kt){
    bool stg = (kt + 1 < ktE);
    if (stg){
      STAGE(kt+1, cur^1);                    // +9 (18 in flight)
      asm volatile("s_waitcnt vmcnt(9)" ::: "memory");   // tile kt's 9 done
    } else {
      asm volatile("s_waitcnt vmcnt(0)" ::: "memory");
    }
    __builtin_amdgcn_s_barrier();            // all waves' kt loads landed
    __builtin_amdgcn_sched_barrier(0);
    const ushort* Ac = &As[cur][0];
    const ushort* Bc = &Bs[cur][0];
    #pragma unroll
    for (int p=0;p<4;p++){                   // 4 k=16 passes within BK=64
      int brow = wn*32 + l31;
      short8 dfr = *(const short8*)(Bc + brow*64 + ((((p<<1)|lh) ^ (brow & 7)) << 3));
      short8 cfr[5];
      #pragma unroll
      for (int a=0;a<5;a++){
        int arow = a*32 + l31;
        cfr[a] = *(const short8*)(Ac + arow*64 + ((((p<<1)|lh) ^ (arow & 7)) << 3));
      }
      __builtin_amdgcn_s_setprio(1);
      #pragma unroll
      for (int a=0;a<5;a++)
        acc[a] = __builtin_amdgcn_mfma_f32_32x32x16_bf16(dfr, cfr[a], acc[a], 0,0,0);
      __builtin_amdgcn_s_setprio(0);
    }
    __builtin_amdgcn_sched_barrier(0);
    __builtin_amdgcn_s_barrier();            // reads of cur done (no vm drain!)
    __builtin_amdgcn_sched_barrier(0);
    cur ^= 1;
  }

  // D layout (32x32): n(q) = lane&31, m(col) = (r&3) + 8*(r>>2) + 4*(lane>>5)
  ushort* pb = part + (size_t)kc*NCOL*QPAD;
  #pragma unroll
  for (int a=0;a<5;a++){
    int q = qh*QH + a*32 + l31;
    int colb = nb*BN + wn*32 + 4*lh;
    #pragma unroll
    for (int r=0;r<16;r++){
      int col = colb + (r&3) + 8*(r>>2);
      pb[(size_t)col*QPAD + q] = bfc(acc[a][r]);
    }
  }
}

// per (b,t) column: partial-sum + nonlinear -> fixed-width banded matvecs -> harmonic gather
__global__ __launch_bounds__(384) void fuse_k(const float* __restrict__ dx,
        const ushort* __restrict__ part,
        const float* __restrict__ WfT, const float* __restrict__ WqT,
        const int* __restrict__ fLo, const int* __restrict__ qLo,
        float* __restrict__ out, int HFI, int HQI){
  __shared__ float xr[2368];
  __shared__ float yq[QPAD];
  __shared__ float tl0[KBINS];
  __shared__ float tlq[KBINS];
  int col = blockIdx.x;
  int b = col >> 9, t = col & 511;
  int tid = threadIdx.x;
  const float invs = 0.011180339887498949f;   // 1/sqrt(8000)

  for (int f = tid; f < 2368; f += 384) xr[f] = (f < HFI) ? dx[(size_t)col*NN + f] : 0.f;
  const ushort* pc = part + (size_t)col*QPAD;
  for (int q = tid; q < QPAD; q += 384){
    float y = 0.f;
    if (q < HQI){
      float s = 0.f;
      #pragma unroll
      for (int kc=0; kc<KC; kc++) s += b2f(pc[(size_t)kc*NCOL*QPAD + q]);
      s *= invs;
      if (q >= CUTQ && s > 0.f) y = powf(s, 0.6f);
    }
    yq[q] = y;
  }
  __syncthreads();

  if (tid < KBINS){
    int k = tid;
    int lo = fLo[k];
    float aF = 0.f;
    #pragma unroll
    for (int j=0;j<WFB;j++) aF += WfT[j*KBINS + k] * xr[lo + j];
    int ql = qLo[k];
    float aQ = 0.f;
    #pragma unroll
    for (int j=0;j<WQB;j++) aQ += WqT[j*KBINS + k] * yq[ql + j];
    tl0[k] = aF; tlq[k] = aQ;
  }
  __syncthreads();

  const int hids[6] = {0,48,76,96,111,124};   // argmin|CF - (k+1)*27.5|
  for (int u = tid; u < 12*KBINS; u += 384){
    int j = u / KBINS;
    int k = u - j*KBINS;
    int h = hids[(j < 6) ? j : j - 6];
    float v;
    if (j < 6) v = (k + h < KBINS) ? tl0[k + h] : 0.f;   // har_s: shift left, pad end
    else       v = (k >= h)        ? tlq[k - h] : 0.f;   // har_c: shift right, pad front
    out[(((size_t)b*12 + j)*T_ + t)*KBINS + k] = v;
  }
}

extern "C" void kernel_launch(void* const* d_in, const int* in_sizes, int n_in,
                              void* d_out, int out_size, void* d_ws, size_t ws_size,
                              hipStream_t stream){
  const float* dx = (const float*)d_in[0];
  const float* Wf = (const float*)d_in[1];
  const float* Wq = (const float*)d_in[2];
  int HFI = in_sizes[1] / KBINS;   // runtime-derived (banker's-rounding safe)
  int HQI = in_sizes[2] / KBINS;
  float* out = (float*)d_out;
  char* ws = (char*)d_ws;

  ushort* cosg = (ushort*)ws;
  size_t off = (size_t)NTILE*QPAD*64*2;                        // 5.24 MB
  ushort* xf = (ushort*)(ws + off); off += (size_t)NTILE*NCOL*64*2;   // 33.55 MB
  ushort* part = (ushort*)(ws + off); off += (size_t)KC*NCOL*QPAD*2;  // 20.97 MB
  int* fLo = (int*)(ws+off); off += KBINS*4;
  int* qLo = (int*)(ws+off); off += KBINS*4;
  float* WfT = (float*)(ws+off); off += (size_t)WFB*KBINS*4;   // 90 KB
  float* WqT = (float*)(ws+off); off += (size_t)WQB*KBINS*4;   // 28 KB
  (void)n_in; (void)out_size; (void)ws_size;

  gen_cos_k<<<dim3(16, QPAD), 256, 0, stream>>>(cosg, HQI);     // n < 4096
  fold_k<<<NCOL, 512, 0, stream>>>(dx, xf);
  bp_k<<<dim3(KBINS, 2), 256, 0, stream>>>(Wf, Wq, HFI, HQI, fLo, qLo, WfT, WqT);
  gemm_k<<<dim3(NCOL/BN, QPAD/QH, KC), 256, 0, stream>>>(xf, cosg, part);
  fuse_k<<<NCOL, 384, 0, stream>>>(dx, part, WfT, WqT, fLo, qLo, out, HFI, HQI);
}

// Round 10
// 128.529 us; speedup vs baseline: 1.1019x; 1.0069x over previous
//
#include <hip/hip_runtime.h>
#include <hip/hip_bf16.h>
#include <limits.h>

typedef __attribute__((ext_vector_type(8))) short short8;
typedef __attribute__((ext_vector_type(4))) float f32x4;
typedef __attribute__((ext_vector_type(16))) float f32x16;

#define NN 8000
#define NCOL 4096      // 8*512 merged columns
#define KBINS 352      // NEST-1 == TOTAL_BINS
#define QPAD 640       // 583 padded
#define QH 320         // q rows per block (2 q-halves)
#define BN 256         // cols per block
#define KC 8           // k chunks (grid 16x2x8 = 256 blocks = 1/CU)
#define NTILE 64       // folded K padded: 64 tiles of 64 (n>4000 zeroed)
#define KSTEP 8        // tiles per chunk: 64 = 8*8 exact
#define CUTQ 4
#define T_ 512
#define WFB 64         // packed band width for W_freq
#define WQB 20         // packed band width for W_quef
#define NGC 2560       // gen_cos blocks in prep_k (640*4096/1024)

#define GLL16(g, l) __builtin_amdgcn_global_load_lds( \
    (const __attribute__((address_space(1))) unsigned int*)(g), \
    (__attribute__((address_space(3))) unsigned int*)(l), 16, 0, 0)

static __device__ __forceinline__ ushort bfc(float f){
  __hip_bfloat16 h = __float2bfloat16(f);
  return *reinterpret_cast<ushort*>(&h);
}
static __device__ __forceinline__ float b2f(ushort u){
  unsigned v = ((unsigned)u) << 16; float f; __builtin_memcpy(&f, &v, 4); return f;
}

#define PADI(j) ((j) + ((j) >> 5))

// merged prep: [0,4096) fold rows; [4096,4096+NGC) cos table; rest band-pack.
__global__ __launch_bounds__(512) void prep_k(const float* __restrict__ dx,
        ushort* __restrict__ xf, ushort* __restrict__ cosg,
        const float* __restrict__ Wf, const float* __restrict__ Wq,
        int HFI, int HQI, int* __restrict__ fLo, int* __restrict__ qLo,
        float* __restrict__ WfT, float* __restrict__ WqT){
  __shared__ float sbuf[4232];                     // PADI(4103)=4231
  __shared__ int slo, shi;
  int bid = blockIdx.x;
  int t = threadIdx.x;

  if (bid < NCOL){
    // ---- symmetric fold: xf[0]=x[0]; xf[n]=x[n]+x[8000-n] (1<=n<4000);
    //      xf[4000]=x[4000]; xf[n>4000]=0; pre-swizzled k-tiled bf16 ----
    int row = bid;
    const float* rp = dx + (size_t)row*NN;
    {
      int j0 = t*8;
      f32x4 v0 = *(const f32x4*)(rp + 3896 + j0);
      f32x4 v1 = *(const f32x4*)(rp + 3896 + j0 + 4);
      #pragma unroll
      for (int e=0;e<4;e++) sbuf[PADI(j0+e)] = v0[e];
      #pragma unroll
      for (int e=0;e<4;e++) sbuf[PADI(j0+4+e)] = v1[e];
      if (t == 0){
        #pragma unroll
        for (int e=0;e<8;e++) sbuf[PADI(4096+e)] = rp[7992+e];
      }
    }
    __syncthreads();
    int n0 = t*8;
    f32x4 p0 = *(const f32x4*)(rp + n0);
    f32x4 p1 = *(const f32x4*)(rp + n0 + 4);
    float pr[8] = {p0[0],p0[1],p0[2],p0[3],p1[0],p1[1],p1[2],p1[3]};
    short8 o;
    #pragma unroll
    for (int e=0;e<8;e++){
      int n = n0 + e;
      float v;
      if (n == 0)          v = pr[0];
      else if (n < 4000)   v = pr[e] + sbuf[PADI(4104 - n)];   // x[8000-n]
      else if (n == 4000)  v = pr[e];
      else                 v = 0.f;
      o[e] = (short)bfc(v);
    }
    int kt = n0 >> 6, s8 = (n0 >> 3) & 7;
    *(short8*)(&xf[((size_t)kt*NCOL + row)*64 + ((s8 ^ (row & 7)) << 3)]) = o;
  } else if (bid < NCOL + NGC){
    // ---- cos table: cosg[kt][q][swizzled 64] = bf16(cos(2pi*((q*n)%8000)/8000)) ----
    int base = (bid - NCOL) * 1024;
    #pragma unroll
    for (int u2=0;u2<2;u2++){
      int id = base + u2*512 + t;                  // < 640*4096
      int q = id >> 12, n = id & 4095;
      float v = 0.f;
      if (q < HQI){
        int m = (q*n) % NN;
        v = cosf((float)m * 7.8539816339744831e-4f);
      }
      int kt = n >> 6, s8 = (n >> 3) & 7, e = n & 7;
      cosg[(size_t)kt*(QPAD*64) + (size_t)q*64 + (((s8 ^ (q & 7)) << 3) | e)] = bfc(v);
    }
  } else {
    // ---- bounds-scan + fixed-width transposed band-pack ----
    int u = bid - NCOL - NGC;                      // 0..703
    int r = u >> 1;
    bool isF = (u & 1) == 0;
    const float* W = isF ? Wf : Wq;
    int width = isF ? HFI : HQI;
    int bw    = isF ? WFB : WQB;
    float* WT = isF ? WfT : WqT;
    int* Lo   = isF ? fLo : qLo;
    if (t==0){ slo = INT_MAX; shi = -1; }
    __syncthreads();
    int mylo = INT_MAX, myhi = -1;
    for (int c = t; c < width; c += 512){
      if (W[(size_t)r*width + c] != 0.f){ if (c < mylo) mylo = c; if (c > myhi) myhi = c; }
    }
    atomicMin(&slo, mylo); atomicMax(&shi, myhi);
    __syncthreads();
    int l = (shi < 0) ? 0 : slo, h = (shi < 0) ? 0 : shi + 1;
    if (t==0) Lo[r] = l;
    for (int j = t; j < bw; j += 512){
      float v = 0.f;
      if (l + j < h) v = W[(size_t)r*width + l + j];
      WT[(size_t)j*KBINS + r] = v;
    }
  }
}

// part[kc][col][q] (bf16) = sum_{k in chunk} xf[col][k]*cos[q][k]
// Block 320q x 256col, BK=64, 8 waves (2 wm x 4 wn), wave tile 160q x 64col
// (5x2 mfma_32x32x16 per pass). dbuf 144KB LDS, 1 block/CU. Pure-GLL staging,
// counted vmcnt(9) at step top (never drain mid-loop), 4 phase barriers/step.
__global__ __launch_bounds__(512, 2) void gemm_k(const ushort* __restrict__ xf,
                                                 const ushort* __restrict__ cosg,
                                                 ushort* __restrict__ part){
  __shared__ ushort As[2][QH*64];    // cos tiles, 40 KB each, slot-swizzled
  __shared__ ushort Bs[2][BN*64];    // folded dx tiles, 32 KB each, slot-swizzled
  int tid = threadIdx.x;
  int nb = blockIdx.x, qh = blockIdx.y, kc = blockIdx.z;
  int lane = tid & 63, widx = tid >> 6;
  int wm = widx & 1, wn = widx >> 1;          // wm: q-half(160), wn: col-quarter(64)
  int l31 = lane & 31, lh = lane >> 5;
  int kt0 = kc*KSTEP, ktE = kt0 + KSTEP;

  const ushort* ag0 = cosg + (size_t)qh*(QH*64) + tid*8;
  const ushort* bg0 = xf + (size_t)nb*(BN*64) + tid*8;

  #define STAGE(kt_, buf_) { \
    const ushort* ag_ = ag0 + (size_t)(kt_)*(QPAD*64); \
    _Pragma("unroll") \
    for (int i_=0;i_<5;i_++) GLL16(ag_ + i_*4096, &As[buf_][tid*8 + i_*4096]); \
    const ushort* bg_ = bg0 + (size_t)(kt_)*(NCOL*64); \
    _Pragma("unroll") \
    for (int i_=0;i_<4;i_++) GLL16(bg_ + i_*4096, &Bs[buf_][tid*8 + i_*4096]); }

  f32x16 acc[5][2];
  #pragma unroll
  for (int a=0;a<5;a++){ acc[a][0] = (f32x16)0.f; acc[a][1] = (f32x16)0.f; }

  STAGE(kt0, 0);                             // 9 loads/thread in flight

  int cur = 0;
  for (int kt = kt0; kt < ktE; ++kt){
    if (kt + 1 < ktE){
      STAGE(kt+1, cur^1);                    // 18 in flight
      asm volatile("s_waitcnt vmcnt(9)" ::: "memory");   // tile kt landed
    } else {
      asm volatile("s_waitcnt vmcnt(0)" ::: "memory");
    }
    __builtin_amdgcn_s_barrier();            // all waves see tile kt
    __builtin_amdgcn_sched_barrier(0);
    const ushort* Ac = &As[cur][0];
    const ushort* Bc = &Bs[cur][0];
    #pragma unroll
    for (int p=0;p<4;p++){                   // 4 k=16 phases within BK=64
      short8 dfr[2];
      #pragma unroll
      for (int c=0;c<2;c++){
        int row = wn*64 + c*32 + l31;
        dfr[c] = *(const short8*)(Bc + row*64 + ((((p<<1)|lh) ^ (row & 7)) << 3));
      }
      short8 cfr[5];
      #pragma unroll
      for (int a=0;a<5;a++){
        int row = wm*160 + a*32 + l31;
        cfr[a] = *(const short8*)(Ac + row*64 + ((((p<<1)|lh) ^ (row & 7)) << 3));
      }
      __builtin_amdgcn_s_setprio(1);
      #pragma unroll
      for (int a=0;a<5;a++){
        acc[a][0] = __builtin_amdgcn_mfma_f32_32x32x16_bf16(dfr[0], cfr[a], acc[a][0], 0,0,0);
        acc[a][1] = __builtin_amdgcn_mfma_f32_32x32x16_bf16(dfr[1], cfr[a], acc[a][1], 0,0,0);
      }
      __builtin_amdgcn_s_setprio(0);
      __builtin_amdgcn_sched_barrier(0);
      __builtin_amdgcn_s_barrier();          // phase lockstep (no vm drain)
      __builtin_amdgcn_sched_barrier(0);
    }
    cur ^= 1;
  }

  // D layout (32x32): n(q) = lane&31, m(col) = (r&3) + 8*(r>>2) + 4*(lane>>5)
  ushort* pb = part + (size_t)kc*NCOL*QPAD;
  #pragma unroll
  for (int a=0;a<5;a++){
    int q = qh*QH + wm*160 + a*32 + l31;
    #pragma unroll
    for (int c=0;c<2;c++){
      int colb = nb*BN + wn*64 + c*32 + 4*lh;
      #pragma unroll
      for (int r=0;r<16;r++){
        int col = colb + (r&3) + 8*(r>>2);
        pb[(size_t)col*QPAD + q] = bfc(acc[a][c][r]);
      }
    }
  }
}

// per (b,t) column: partial-sum + nonlinear -> fixed-width banded matvecs -> harmonic gather
__global__ __launch_bounds__(384) void fuse_k(const float* __restrict__ dx,
        const ushort* __restrict__ part,
        const float* __restrict__ WfT, const float* __restrict__ WqT,
        const int* __restrict__ fLo, const int* __restrict__ qLo,
        float* __restrict__ out, int HFI, int HQI){
  __shared__ float xr[2368];
  __shared__ float yq[QPAD];
  __shared__ float tl0[KBINS];
  __shared__ float tlq[KBINS];
  int col = blockIdx.x;
  int b = col >> 9, t = col & 511;
  int tid = threadIdx.x;
  const float invs = 0.011180339887498949f;   // 1/sqrt(8000)

  for (int f = tid; f < 2368; f += 384) xr[f] = (f < HFI) ? dx[(size_t)col*NN + f] : 0.f;
  const ushort* pc = part + (size_t)col*QPAD;
  for (int q = tid; q < QPAD; q += 384){
    float y = 0.f;
    if (q < HQI){
      float s = 0.f;
      #pragma unroll
      for (int kc=0; kc<KC; kc++) s += b2f(pc[(size_t)kc*NCOL*QPAD + q]);
      s *= invs;
      if (q >= CUTQ && s > 0.f) y = powf(s, 0.6f);
    }
    yq[q] = y;
  }
  __syncthreads();

  if (tid < KBINS){
    int k = tid;
    int lo = fLo[k];
    float aF = 0.f;
    #pragma unroll
    for (int j=0;j<WFB;j++) aF += WfT[j*KBINS + k] * xr[lo + j];
    int ql = qLo[k];
    float aQ = 0.f;
    #pragma unroll
    for (int j=0;j<WQB;j++) aQ += WqT[j*KBINS + k] * yq[ql + j];
    tl0[k] = aF; tlq[k] = aQ;
  }
  __syncthreads();

  const int hids[6] = {0,48,76,96,111,124};   // argmin|CF - (k+1)*27.5|
  for (int u = tid; u < 12*KBINS; u += 384){
    int j = u / KBINS;
    int k = u - j*KBINS;
    int h = hids[(j < 6) ? j : j - 6];
    float v;
    if (j < 6) v = (k + h < KBINS) ? tl0[k + h] : 0.f;   // har_s: shift left, pad end
    else       v = (k >= h)        ? tlq[k - h] : 0.f;   // har_c: shift right, pad front
    out[(((size_t)b*12 + j)*T_ + t)*KBINS + k] = v;
  }
}

extern "C" void kernel_launch(void* const* d_in, const int* in_sizes, int n_in,
                              void* d_out, int out_size, void* d_ws, size_t ws_size,
                              hipStream_t stream){
  const float* dx = (const float*)d_in[0];
  const float* Wf = (const float*)d_in[1];
  const float* Wq = (const float*)d_in[2];
  int HFI = in_sizes[1] / KBINS;   // runtime-derived (banker's-rounding safe)
  int HQI = in_sizes[2] / KBINS;
  float* out = (float*)d_out;
  char* ws = (char*)d_ws;

  ushort* cosg = (ushort*)ws;
  size_t off = (size_t)NTILE*QPAD*64*2;                        // 5.24 MB
  ushort* xf = (ushort*)(ws + off); off += (size_t)NTILE*NCOL*64*2;   // 33.55 MB
  ushort* part = (ushort*)(ws + off); off += (size_t)KC*NCOL*QPAD*2;  // 41.94 MB
  int* fLo = (int*)(ws+off); off += KBINS*4;
  int* qLo = (int*)(ws+off); off += KBINS*4;
  float* WfT = (float*)(ws+off); off += (size_t)WFB*KBINS*4;   // 90 KB
  float* WqT = (float*)(ws+off); off += (size_t)WQB*KBINS*4;   // 28 KB
  (void)n_in; (void)out_size; (void)ws_size;

  prep_k<<<NCOL + NGC + 2*KBINS, 512, 0, stream>>>(dx, xf, cosg, Wf, Wq,
                                                   HFI, HQI, fLo, qLo, WfT, WqT);
  gemm_k<<<dim3(NCOL/BN, QPAD/QH, KC), 512, 0, stream>>>(xf, cosg, part);
  fuse_k<<<NCOL, 384, 0, stream>>>(dx, part, WfT, WqT, fLo, qLo, out, HFI, HQI);
}